// Round 15
// baseline (603.550 us; speedup 1.0000x reference)
//
#include <hip/hip_runtime.h>

// ---------------------------------------------------------------------------
// RoPE Multihead Self-Attention  B=4 S=2048 E=1024 H=16 D=64  (bf16 internal)
// ---------------------------------------------------------------------------

typedef __attribute__((ext_vector_type(4))) float f32x4;
typedef __attribute__((ext_vector_type(16))) float f32x16;
typedef __attribute__((ext_vector_type(8))) short bfrag;   // 8 x bf16 (4 VGPR)
typedef __attribute__((ext_vector_type(4))) short svec4;
typedef __attribute__((ext_vector_type(4))) unsigned u32x4;

#define MFMA16(a, b, c) __builtin_amdgcn_mfma_f32_16x16x32_bf16(a, b, c, 0, 0, 0)
#define MFMA32(a, b, c) __builtin_amdgcn_mfma_f32_32x32x16_bf16(a, b, c, 0, 0, 0)

__device__ __forceinline__ unsigned short f2bf(float f) {
  unsigned u = __builtin_bit_cast(unsigned, f);
  u += 0x7FFFu + ((u >> 16) & 1u);            // round-to-nearest-even
  return (unsigned short)(u >> 16);
}

// async global->LDS, 16B per lane
__device__ __forceinline__ void gload16(const void* g, void* l) {
  __builtin_amdgcn_global_load_lds(
      (const __attribute__((address_space(1))) unsigned int*)g,
      (__attribute__((address_space(3))) unsigned int*)l, 16, 0, 0);
}

// exp2 + row-sum + bf16-pack + cross-half shfl: turns one 32-key S-block
// (f32x16) into two 16-key PV A-fragments.  Verified in round 14 (passed).
__device__ __forceinline__ void exppack(f32x16& sc, float& ls, int th,
                                        bfrag& paA, bfrag& paB) {
#pragma unroll
  for (int i = 0; i < 16; ++i) sc[i] = __builtin_amdgcn_exp2f(sc[i]);
  ls += ((sc[0] + sc[1]) + (sc[2] + sc[3])) + ((sc[4] + sc[5]) + (sc[6] + sc[7])) +
        ((sc[8] + sc[9]) + (sc[10] + sc[11])) + ((sc[12] + sc[13]) + (sc[14] + sc[15]));
  unsigned pk[4][2];
#pragma unroll
  for (int gg = 0; gg < 4; ++gg) {
    asm("v_cvt_pk_bf16_f32 %0, %1, %2"
        : "=v"(pk[gg][0]) : "v"(sc[4 * gg]), "v"(sc[4 * gg + 1]));
    asm("v_cvt_pk_bf16_f32 %0, %1, %2"
        : "=v"(pk[gg][1]) : "v"(sc[4 * gg + 2]), "v"(sc[4 * gg + 3]));
  }
  u32x4 puA, puB;
#pragma unroll
  for (int j = 0; j < 2; ++j) {
    unsigned zlo = pk[0][j], zhi = pk[1][j];
    unsigned zsend = th ? zlo : zhi;
    unsigned wv = (unsigned)__shfl_xor((int)zsend, 32);
    puA[j]     = th ? wv : zlo;
    puA[2 + j] = th ? zhi : wv;
  }
#pragma unroll
  for (int j = 0; j < 2; ++j) {
    unsigned zlo = pk[2][j], zhi = pk[3][j];
    unsigned zsend = th ? zlo : zhi;
    unsigned wv = (unsigned)__shfl_xor((int)zsend, 32);
    puB[j]     = th ? wv : zlo;
    puB[2 + j] = th ? zhi : wv;
  }
  paA = __builtin_bit_cast(bfrag, puA);
  paB = __builtin_bit_cast(bfrag, puB);
}

// ---------------------------------------------------------------------------
// K0: fp32 -> bf16 conversion of x and 4 weights + RoPE cos/sin table
// ---------------------------------------------------------------------------
__global__ __launch_bounds__(256) void prep_kernel(
    const float* __restrict__ x, const float* __restrict__ wq,
    const float* __restrict__ wk, const float* __restrict__ wv,
    const float* __restrict__ wo,
    unsigned short* __restrict__ xb, unsigned short* __restrict__ wqb,
    unsigned short* __restrict__ wkb, unsigned short* __restrict__ wvb,
    unsigned short* __restrict__ wob, float2* __restrict__ rope) {
  const int y = blockIdx.y;
  const int tid = blockIdx.x * blockDim.x + threadIdx.x;
  const int stride = gridDim.x * blockDim.x;
  if (y < 5) {
    const float* src = y == 0 ? x : y == 1 ? wq : y == 2 ? wk : y == 3 ? wv : wo;
    unsigned short* dst = y == 0 ? xb : y == 1 ? wqb : y == 2 ? wkb : y == 3 ? wvb : wob;
    const int n4 = (y == 0 ? (8192 * 1024) : (1024 * 1024)) >> 2;
    for (int i = tid; i < n4; i += stride) {
      float4 v = ((const float4*)src)[i];
      svec4 o;
      o.x = (short)f2bf(v.x); o.y = (short)f2bf(v.y);
      o.z = (short)f2bf(v.z); o.w = (short)f2bf(v.w);
      ((svec4*)dst)[i] = o;
    }
  } else {
    for (int i = tid; i < 2048 * 32; i += stride) {
      int s = i >> 5, f = i & 31;
      float invf = powf(10000.0f, -(float)f * (1.0f / 32.0f));
      float ang = (float)s * invf;
      rope[i] = make_float2(cosf(ang), sinf(ang));
    }
  }
}

// ---------------------------------------------------------------------------
// K1: QKV projection GEMM with fused RoPE (Q,K) and fused transpose (V).
// ---------------------------------------------------------------------------
__global__ __launch_bounds__(256) void gemm_qkv(
    const unsigned short* __restrict__ Xb,
    const unsigned short* __restrict__ Wq, const unsigned short* __restrict__ Wk,
    const unsigned short* __restrict__ Wv,
    const float* __restrict__ biasq, const float* __restrict__ biask,
    const float* __restrict__ biasv,
    const float2* __restrict__ rope,
    unsigned short* __restrict__ Qo, unsigned short* __restrict__ Ko,
    unsigned short* __restrict__ Vto) {
  const int z = blockIdx.z;
  __shared__ unsigned short As[128 * 64];
  __shared__ unsigned short Bs[128 * 64];
  const int t = threadIdx.x;
  const int lane = t & 63, w = t >> 6;
  const int wr = w >> 1, wc = w & 1;
  const int lc = lane & 15, lr = lane >> 4;

  int m0, n0;
  const unsigned short *Apt, *Bpt;
  if (z == 0)      { m0 = blockIdx.y * 128; n0 = blockIdx.x * 128; Apt = Xb; Bpt = Wq; }
  else if (z == 1) { m0 = blockIdx.y * 128; n0 = blockIdx.x * 128; Apt = Xb; Bpt = Wk; }
  else             { m0 = blockIdx.x * 128; n0 = blockIdx.y * 128; Apt = Wv; Bpt = Xb; }

  const int arow = t >> 3;
  const int acol = ((t & 7) << 3) ^ ((arow & 7) << 3);   // pre-swizzled source col
  const unsigned short* gA = Apt + (size_t)(m0 + arow) * 1024 + acol;
  const unsigned short* gB = Bpt + (size_t)(n0 + arow) * 1024 + acol;
  unsigned short* lA = As + t * 8;
  unsigned short* lB = Bs + t * 8;

  f32x4 acc[4][4];
#pragma unroll
  for (int m = 0; m < 4; ++m)
#pragma unroll
    for (int n = 0; n < 4; ++n) acc[m][n] = (f32x4){0.f, 0.f, 0.f, 0.f};

  const int rsw = (lc & 7) << 3;

#pragma unroll 1
  for (int kt = 0; kt < 16; ++kt) {
    __syncthreads();
#pragma unroll
    for (int c = 0; c < 4; ++c) {
      gload16(gA + (size_t)c * 32 * 1024, lA + c * 2048);
      gload16(gB + (size_t)c * 32 * 1024, lB + c * 2048);
    }
    gA += 64; gB += 64;
    __syncthreads();
#pragma unroll
    for (int ks = 0; ks < 2; ++ks) {
      bfrag af[4], bfr[4];
#pragma unroll
      for (int i = 0; i < 4; ++i)
        af[i] = *(const bfrag*)(As + (wr * 64 + i * 16 + lc) * 64 + ((ks * 32 + lr * 8) ^ rsw));
#pragma unroll
      for (int i = 0; i < 4; ++i)
        bfr[i] = *(const bfrag*)(Bs + (wc * 64 + i * 16 + lc) * 64 + ((ks * 32 + lr * 8) ^ rsw));
#pragma unroll
      for (int m = 0; m < 4; ++m)
#pragma unroll
        for (int n = 0; n < 4; ++n)
          acc[m][n] = MFMA16(af[m], bfr[n], acc[m][n]);
    }
  }

  if (z < 2) {
    // bias + RoPE + (Q only) 0.125*log2e scale; scatter to (B,H,S,D)
    const float* bias = (z == 0) ? biasq : biask;
    unsigned short* dst = (z == 0) ? Qo : Ko;
    const float qs = (z == 0) ? 0.125f * 1.44269504f : 1.0f;
    const int h = (n0 + wc * 64) >> 6;
#pragma unroll
    for (int m = 0; m < 4; ++m) {
#pragma unroll
      for (int r = 0; r < 4; ++r) {
        int row = m0 + wr * 64 + m * 16 + lr * 4 + r;   // token
        int b = row >> 11, s = row & 2047;
        const float2* trow = rope + (s << 5);
        size_t base = ((size_t)((b << 4) + h) * 2048 + s) * 64;
#pragma unroll
        for (int n = 0; n < 2; ++n) {
          int col1 = n0 + wc * 64 + n * 16 + lc;
          int d = n * 16 + lc;                           // < 32
          float a  = acc[m][n][r]     + bias[col1];
          float bb = acc[m][n + 2][r] + bias[col1 + 32];
          float2 t0 = trow[d >> 1];
          float2 t1 = trow[16 + (d >> 1)];
          dst[base + d]      = f2bf((a * t0.x - bb * t0.y) * qs);
          dst[base + d + 32] = f2bf((bb * t1.x + a * t1.y) * qs);
        }
      }
    }
  } else {
    // V: C[wcol][token] -> Vt (B,H,D,S)
#pragma unroll
    for (int m = 0; m < 4; ++m) {
#pragma unroll
      for (int r = 0; r < 4; ++r) {
        int wcol = m0 + wr * 64 + m * 16 + lr * 4 + r;
        float bv = biasv[wcol];
        int h = wcol >> 6, d = wcol & 63;
#pragma unroll
        for (int n = 0; n < 4; ++n) {
          int token = n0 + wc * 64 + n * 16 + lc;
          int b = token >> 11, s = token & 2047;
          Vto[((size_t)((b << 4) + h) * 64 + d) * 2048 + s] = f2bf(acc[m][n][r] + bv);
        }
      }
    }
  }
}

// ---------------------------------------------------------------------------
// K4: flash attention, IN-BLOCK SPLIT-K.  8 waves (512 thr): waves 0-3 process
// keys [0,1024), waves 4-7 keys [1024,2048) for the SAME 256 q-rows; partial
// (unnormalized O, lsum) combined through LDS at the end.  Doubles wave count
// (2048 -> 4096 = 4 waves/SIMD) at UNCHANGED per-key instruction cost — the
// only remaining mechanism after r13/r14 showed per-wave ILP can't hide r12's
// ~35% dependency stall (3734 cyc/iter-pair wall vs ~2500 pipe demand).
// Per-wave body = r12's verified 64q 32x32 in-register-P structure, halved
// to KVBLK=32.  LDS = 2buf x 16KB (K0|V0|K1|V1, linear-dest staging with
// pre-swizzled source, rule #21) + 1KB lsum = 33KB -> 2 blocks/CU.
// No-max softmax (r4-r14 proven).  Counted-vmcnt 2-deep prefetch.
// ---------------------------------------------------------------------------
__global__ __launch_bounds__(512, 4) void attn_kernel(
    const unsigned short* __restrict__ Q, const unsigned short* __restrict__ K,
    const unsigned short* __restrict__ Vt, unsigned short* __restrict__ O) {
  __shared__ unsigned short SMEM[2][8192];   // [buf][16KB]: K0|V0|K1|V1
  __shared__ float lsx[4][2][32];
  const int t = threadIdx.x;
  const int lane = t & 63, w = t >> 6;        // 8 waves
  const int half = w >> 2, wq = w & 3;        // key-half, q-slot
  const int l31 = lane & 31, th = lane >> 5;
  const int bid = blockIdx.x;                 // 512 = 8 xcd x 8 head x 8 qb
  const int xcd = bid & 7;
  const int jj = bid >> 3;                    // 0..63
  const int bh = xcd * 8 + (jj >> 3);         // 8 heads per XCD -> L2-resident
  const int qb = jj & 7;
  const int q0 = qb * 256 + wq * 64;          // 64 q-rows per wave

  // Q B-fragments: bq{g}[kk] = Q[q=q0+g*32+l31][d = kk*16 + th*8 .. +7]
  const unsigned short* Qp = Q + ((size_t)bh * 2048 + q0 + l31) * 64 + th * 8;
  bfrag bq0[4], bq1[4];
#pragma unroll
  for (int kk = 0; kk < 4; ++kk) {
    bq0[kk] = *(const bfrag*)(Qp + kk * 16);
    bq1[kk] = *(const bfrag*)(Qp + 32 * 64 + kk * 16);
  }

  f32x16 acc00, acc01, acc10, acc11;   // acc{g}{db}
#pragma unroll
  for (int i = 0; i < 16; ++i) {
    acc00[i] = 0.f; acc01[i] = 0.f; acc10[i] = 0.f; acc11[i] = 0.f;
  }
  float lsum0 = 0.f, lsum1 = 0.f;

  const unsigned short* KgB = K + (size_t)bh * 2048 * 64;    // key-major [2048][64]
  const unsigned short* VgB = Vt + (size_t)bh * 64 * 2048;   // d-major  [64][2048]

  // staging: thread t covers 16B unit t (load0: half0) and unit 512+t (load1:
  // half1).  Units 0-255 = K tile [32 rows][8 slots], 256-511 = V tile
  // [64 rows][4 slots].  Source col pre-swizzled; LDS dest linear in t.
  const int isK = (t < 256) ? 1 : 0;
  const int kr = (t & 255) >> 3, kc = t & 7;       // K: row (key), col-slot
  const int vd = (t & 255) >> 2, vk = t & 3;       // V: row (d), k-slot
  const int kofs = ((kc ^ (kr & 7)) << 3);
  const int vofs = ((vk ^ ((vd >> 1) & 3)) << 3);

#define STAGE(bufi, kb_)                                                         \
  {                                                                              \
    gload16(isK ? (const void*)(KgB + (size_t)((kb_) + kr) * 64 + kofs)          \
                : (const void*)(VgB + (size_t)vd * 2048 + (kb_) + vofs),         \
            SMEM[bufi] + t * 8);                                                 \
    gload16(isK ? (const void*)(KgB + (size_t)(1024 + (kb_) + kr) * 64 + kofs)   \
                : (const void*)(VgB + (size_t)vd * 2048 + 1024 + (kb_) + vofs),  \
            SMEM[bufi] + 4096 + t * 8);                                          \
  }

  STAGE(0, 0);
  STAGE(1, 32);
  int cur = 0;

  const unsigned short* KsH = &SMEM[0][0] + half * 4096;   // this wave's K tile
  const unsigned short* VsH = KsH + 2048;                  // this wave's V tile
  const int vsw = (l31 >> 1) & 3;                          // V read swizzle

#pragma unroll 1
  for (int kt = 0; kt < 32; ++kt) {
    if (kt < 30) { asm volatile("s_waitcnt vmcnt(2)" ::: "memory"); }
    else         { asm volatile("s_waitcnt vmcnt(0)" ::: "memory"); }
    __builtin_amdgcn_s_barrier();

    const unsigned short* KsC = KsH + cur * 8192;
    const unsigned short* VsC = VsH + cur * 8192;

    // fragment loads: K rows = keys (32), V rows = d (64), k in [0,32)
    bfrag ka[4], vb00, vb01, vb10, vb11;   // vb{kg}{db}
#pragma unroll
    for (int kk = 0; kk < 4; ++kk)
      ka[kk] = *(const bfrag*)(KsC + (l31 << 6) + (((kk * 2 + th) ^ (l31 & 7)) << 3));
    vb00 = *(const bfrag*)(VsC + l31 * 32        + (((0 * 2 + th) ^ vsw) << 3));
    vb01 = *(const bfrag*)(VsC + (32 + l31) * 32 + (((0 * 2 + th) ^ vsw) << 3));
    vb10 = *(const bfrag*)(VsC + l31 * 32        + (((1 * 2 + th) ^ vsw) << 3));
    vb11 = *(const bfrag*)(VsC + (32 + l31) * 32 + (((1 * 2 + th) ^ vsw) << 3));

    // S^T blocks (rows = 32 keys, cols = 32 q) for both q-groups
    f32x16 sc0, sc1;
#pragma unroll
    for (int i = 0; i < 16; ++i) { sc0[i] = 0.f; sc1[i] = 0.f; }
    __builtin_amdgcn_s_setprio(1);
#pragma unroll
    for (int kk = 0; kk < 4; ++kk) {
      sc0 = MFMA32(ka[kk], bq0[kk], sc0);
      sc1 = MFMA32(ka[kk], bq1[kk], sc1);
    }
    __builtin_amdgcn_s_setprio(0);

    bfrag pa0A, pa0B, pa1A, pa1B;
    exppack(sc0, lsum0, th, pa0A, pa0B);
    exppack(sc1, lsum1, th, pa1A, pa1B);

    __builtin_amdgcn_s_setprio(1);
    acc00 = MFMA32(pa0A, vb00, acc00);
    acc01 = MFMA32(pa0A, vb01, acc01);
    acc10 = MFMA32(pa1A, vb00, acc10);
    acc11 = MFMA32(pa1A, vb01, acc11);
    acc00 = MFMA32(pa0B, vb10, acc00);
    acc01 = MFMA32(pa0B, vb11, acc01);
    acc10 = MFMA32(pa1B, vb10, acc10);
    acc11 = MFMA32(pa1B, vb11, acc11);
    __builtin_amdgcn_s_setprio(0);

    __builtin_amdgcn_s_barrier();
    if (kt + 2 < 32) STAGE(cur, (kt + 2) * 32);
    cur ^= 1;
  }
#undef STAGE

  // per-wave row-sums over this wave's key half
  float v0 = lsum0 + __shfl_xor(lsum0, 32);   // q = q0 + l31
  float v1 = lsum1 + __shfl_xor(lsum1, 32);   // q = q0 + 32 + l31

  // in-block combine: upper waves (half=1) pass partials through LDS.
  // Two rounds (g=0,1), each exactly 32 KB = 4 waves x 64 lanes x 128 B.
  float* smf = (float*)&SMEM[0][0];
  // ---- round g=0
  if (w >= 4) {
    lsx[w - 4][0][l31] = v0;
#pragma unroll
    for (int c = 0; c < 4; ++c) {
      f32x4 ch = {acc00[4 * c], acc00[4 * c + 1], acc00[4 * c + 2], acc00[4 * c + 3]};
      *(f32x4*)(smf + (w - 4) * 2048 + c * 256 + lane * 4) = ch;
    }
#pragma unroll
    for (int c = 0; c < 4; ++c) {
      f32x4 ch = {acc01[4 * c], acc01[4 * c + 1], acc01[4 * c + 2], acc01[4 * c + 3]};
      *(f32x4*)(smf + (w - 4) * 2048 + (c + 4) * 256 + lane * 4) = ch;
    }
  }
  __builtin_amdgcn_s_barrier();
  float vu0 = 0.f, vu1 = 0.f;
  if (w < 4) {
    vu0 = lsx[w][0][l31];
#pragma unroll
    for (int c = 0; c < 4; ++c) {
      f32x4 ch = *(const f32x4*)(smf + w * 2048 + c * 256 + lane * 4);
      acc00[4 * c] += ch[0]; acc00[4 * c + 1] += ch[1];
      acc00[4 * c + 2] += ch[2]; acc00[4 * c + 3] += ch[3];
    }
#pragma unroll
    for (int c = 0; c < 4; ++c) {
      f32x4 ch = *(const f32x4*)(smf + w * 2048 + (c + 4) * 256 + lane * 4);
      acc01[4 * c] += ch[0]; acc01[4 * c + 1] += ch[1];
      acc01[4 * c + 2] += ch[2]; acc01[4 * c + 3] += ch[3];
    }
  }
  __builtin_amdgcn_s_barrier();
  // ---- round g=1
  if (w >= 4) {
    lsx[w - 4][1][l31] = v1;
#pragma unroll
    for (int c = 0; c < 4; ++c) {
      f32x4 ch = {acc10[4 * c], acc10[4 * c + 1], acc10[4 * c + 2], acc10[4 * c + 3]};
      *(f32x4*)(smf + (w - 4) * 2048 + c * 256 + lane * 4) = ch;
    }
#pragma unroll
    for (int c = 0; c < 4; ++c) {
      f32x4 ch = {acc11[4 * c], acc11[4 * c + 1], acc11[4 * c + 2], acc11[4 * c + 3]};
      *(f32x4*)(smf + (w - 4) * 2048 + (c + 4) * 256 + lane * 4) = ch;
    }
  }
  __builtin_amdgcn_s_barrier();
  if (w < 4) {
    vu1 = lsx[w][1][l31];
#pragma unroll
    for (int c = 0; c < 4; ++c) {
      f32x4 ch = *(const f32x4*)(smf + w * 2048 + c * 256 + lane * 4);
      acc10[4 * c] += ch[0]; acc10[4 * c + 1] += ch[1];
      acc10[4 * c + 2] += ch[2]; acc10[4 * c + 3] += ch[3];
    }
#pragma unroll
    for (int c = 0; c < 4; ++c) {
      f32x4 ch = *(const f32x4*)(smf + w * 2048 + (c + 4) * 256 + lane * 4);
      acc11[4 * c] += ch[0]; acc11[4 * c + 1] += ch[1];
      acc11[4 * c + 2] += ch[2]; acc11[4 * c + 3] += ch[3];
    }

    // normalize + store O (B,S,H,D), lower waves only
    float inv0 = 1.0f / (v0 + vu0);
    float inv1 = 1.0f / (v1 + vu1);
    const int b = bh >> 4, h = bh & 15;
#pragma unroll
    for (int r = 0; r < 16; ++r) {
      int qrow = (r & 3) + 8 * (r >> 2) + 4 * th;
      float invr0 = __shfl(inv0, qrow);
      float invr1 = __shfl(inv1, qrow);
      size_t base0 = (((size_t)b * 2048 + q0 + qrow) * 16 + h) * 64 + l31;
      size_t base1 = (((size_t)b * 2048 + q0 + 32 + qrow) * 16 + h) * 64 + l31;
      O[base0]      = f2bf(acc00[r] * invr0);
      O[base0 + 32] = f2bf(acc01[r] * invr0);
      O[base1]      = f2bf(acc10[r] * invr1);
      O[base1 + 32] = f2bf(acc11[r] * invr1);
    }
  }
}

// ---------------------------------------------------------------------------
// K5: output projection.  out = O @ Wo^T + bo   (fp32 out, row-major 8192x1024)
// ---------------------------------------------------------------------------
__global__ __launch_bounds__(256) void gemm_out(
    const unsigned short* __restrict__ Ob, const unsigned short* __restrict__ Wo,
    const float* __restrict__ bias, float* __restrict__ out) {
  __shared__ unsigned short As[128 * 64];
  __shared__ unsigned short Bs[128 * 64];
  const int t = threadIdx.x;
  const int lane = t & 63, w = t >> 6;
  const int wr = w >> 1, wc = w & 1;
  const int lc = lane & 15, lr = lane >> 4;
  const int m0 = blockIdx.y * 128, n0 = blockIdx.x * 128;

  const int arow = t >> 3;
  const int acol = ((t & 7) << 3) ^ ((arow & 7) << 3);
  const unsigned short* gA = Ob + (size_t)(m0 + arow) * 1024 + acol;
  const unsigned short* gB = Wo + (size_t)(n0 + arow) * 1024 + acol;
  unsigned short* lA = As + t * 8;
  unsigned short* lB = Bs + t * 8;

  f32x4 acc[4][4];
#pragma unroll
  for (int m = 0; m < 4; ++m)
#pragma unroll
    for (int n = 0; n < 4; ++n) acc[m][n] = (f32x4){0.f, 0.f, 0.f, 0.f};

  const int rsw = (lc & 7) << 3;

#pragma unroll 1
  for (int kt = 0; kt < 16; ++kt) {
    __syncthreads();
#pragma unroll
    for (int c = 0; c < 4; ++c) {
      gload16(gA + (size_t)c * 32 * 1024, lA + c * 2048);
      gload16(gB + (size_t)c * 32 * 1024, lB + c * 2048);
    }
    gA += 64; gB += 64;
    __syncthreads();
#pragma unroll
    for (int ks = 0; ks < 2; ++ks) {
      bfrag af[4], bfr[4];
#pragma unroll
      for (int i = 0; i < 4; ++i)
        af[i] = *(const bfrag*)(As + (wr * 64 + i * 16 + lc) * 64 + ((ks * 32 + lr * 8) ^ rsw));
#pragma unroll
      for (int i = 0; i < 4; ++i)
        bfr[i] = *(const bfrag*)(Bs + (wc * 64 + i * 16 + lc) * 64 + ((ks * 32 + lr * 8) ^ rsw));
#pragma unroll
      for (int m = 0; m < 4; ++m)
#pragma unroll
        for (int n = 0; n < 4; ++n)
          acc[m][n] = MFMA16(af[m], bfr[n], acc[m][n]);
    }
  }
#pragma unroll
  for (int n = 0; n < 4; ++n) {
    int col = n0 + wc * 64 + n * 16 + lc;
    float bv = bias[col];
#pragma unroll
    for (int m = 0; m < 4; ++m) {
#pragma unroll
      for (int r = 0; r < 4; ++r) {
        int row = m0 + wr * 64 + m * 16 + lr * 4 + r;
        out[(size_t)row * 1024 + col] = acc[m][n][r] + bv;
      }
    }
  }
}

// ---------------------------------------------------------------------------
extern "C" void kernel_launch(void* const* d_in, const int* in_sizes, int n_in,
                              void* d_out, int out_size, void* d_ws, size_t ws_size,
                              hipStream_t stream) {
  (void)in_sizes; (void)n_in; (void)out_size; (void)ws_size;
  const float* x  = (const float*)d_in[0];
  const float* wq = (const float*)d_in[1];
  const float* bq = (const float*)d_in[2];
  const float* wk = (const float*)d_in[3];
  const float* bk = (const float*)d_in[4];
  const float* wv = (const float*)d_in[5];
  const float* bv = (const float*)d_in[6];
  const float* wo = (const float*)d_in[7];
  const float* bo = (const float*)d_in[8];
  float* out = (float*)d_out;

  char* ws = (char*)d_ws;
  unsigned short* Xb   = (unsigned short*)(ws);                       // 16 MB (reused as O)
  unsigned short* Wqb  = (unsigned short*)(ws + (16ull << 20));       // 2 MB
  unsigned short* Wkb  = (unsigned short*)(ws + (18ull << 20));
  unsigned short* Wvb  = (unsigned short*)(ws + (20ull << 20));
  unsigned short* Wob  = (unsigned short*)(ws + (22ull << 20));
  unsigned short* Qb   = (unsigned short*)(ws + (24ull << 20));       // 16 MB
  unsigned short* Kb   = (unsigned short*)(ws + (40ull << 20));       // 16 MB
  unsigned short* Vt   = (unsigned short*)(ws + (56ull << 20));       // 16 MB (B,H,D,S)
  float2* rope         = (float2*)(ws + (72ull << 20));               // 512 KB
  unsigned short* Ob   = Xb;   // Xb dead after QKV GEMM

  prep_kernel<<<dim3(1024, 6), 256, 0, stream>>>(x, wq, wk, wv, wo,
                                                 Xb, Wqb, Wkb, Wvb, Wob, rope);
  gemm_qkv<<<dim3(8, 64, 3), 256, 0, stream>>>(Xb, Wqb, Wkb, Wvb,
                                               bq, bk, bv, rope, Qb, Kb, Vt);
  attn_kernel<<<512, 512, 0, stream>>>(Qb, Kb, Vt, Ob);
  gemm_out<<<dim3(8, 64), 256, 0, stream>>>(Ob, Wob, bo, out);
}

// Round 16
// 195.321 us; speedup vs baseline: 3.0900x; 3.0900x over previous
//
#include <hip/hip_runtime.h>

// ---------------------------------------------------------------------------
// RoPE Multihead Self-Attention  B=4 S=2048 E=1024 H=16 D=64  (bf16 internal)
// ---------------------------------------------------------------------------

typedef __attribute__((ext_vector_type(4))) float f32x4;
typedef __attribute__((ext_vector_type(16))) float f32x16;
typedef __attribute__((ext_vector_type(8))) short bfrag;   // 8 x bf16 (4 VGPR)
typedef __attribute__((ext_vector_type(4))) short svec4;
typedef __attribute__((ext_vector_type(4))) unsigned u32x4;

#define MFMA16(a, b, c) __builtin_amdgcn_mfma_f32_16x16x32_bf16(a, b, c, 0, 0, 0)
#define MFMA32(a, b, c) __builtin_amdgcn_mfma_f32_32x32x16_bf16(a, b, c, 0, 0, 0)

__device__ __forceinline__ unsigned short f2bf(float f) {
  unsigned u = __builtin_bit_cast(unsigned, f);
  u += 0x7FFFu + ((u >> 16) & 1u);            // round-to-nearest-even
  return (unsigned short)(u >> 16);
}

// async global->LDS, 16B per lane
__device__ __forceinline__ void gload16(const void* g, void* l) {
  __builtin_amdgcn_global_load_lds(
      (const __attribute__((address_space(1))) unsigned int*)g,
      (__attribute__((address_space(3))) unsigned int*)l, 16, 0, 0);
}

// ---------------------------------------------------------------------------
// K0: fp32 -> bf16 conversion of x and 4 weights + RoPE cos/sin table
// ---------------------------------------------------------------------------
__global__ __launch_bounds__(256) void prep_kernel(
    const float* __restrict__ x, const float* __restrict__ wq,
    const float* __restrict__ wk, const float* __restrict__ wv,
    const float* __restrict__ wo,
    unsigned short* __restrict__ xb, unsigned short* __restrict__ wqb,
    unsigned short* __restrict__ wkb, unsigned short* __restrict__ wvb,
    unsigned short* __restrict__ wob, float2* __restrict__ rope) {
  const int y = blockIdx.y;
  const int tid = blockIdx.x * blockDim.x + threadIdx.x;
  const int stride = gridDim.x * blockDim.x;
  if (y < 5) {
    const float* src = y == 0 ? x : y == 1 ? wq : y == 2 ? wk : y == 3 ? wv : wo;
    unsigned short* dst = y == 0 ? xb : y == 1 ? wqb : y == 2 ? wkb : y == 3 ? wvb : wob;
    const int n4 = (y == 0 ? (8192 * 1024) : (1024 * 1024)) >> 2;
    for (int i = tid; i < n4; i += stride) {
      float4 v = ((const float4*)src)[i];
      svec4 o;
      o.x = (short)f2bf(v.x); o.y = (short)f2bf(v.y);
      o.z = (short)f2bf(v.z); o.w = (short)f2bf(v.w);
      ((svec4*)dst)[i] = o;
    }
  } else {
    for (int i = tid; i < 2048 * 32; i += stride) {
      int s = i >> 5, f = i & 31;
      float invf = powf(10000.0f, -(float)f * (1.0f / 32.0f));
      float ang = (float)s * invf;
      rope[i] = make_float2(cosf(ang), sinf(ang));
    }
  }
}

// ---------------------------------------------------------------------------
// K1: QKV projection GEMM with fused RoPE (Q,K) and fused transpose (V).
// 1D grid, XCD-GROUPED (T1): bid = xg*192 + j, j = z*64 + yb.  All 8 xg-blocks
// of one (yb,z) strip have bid = j (mod 8) -> same XCD -> the shared 256 KB
// A-strip (X for z<2, Wv/Xb panels for z=2) stays L2-resident instead of
// being re-fetched by 8 XCDs.  Bijective: 1536 = 8 x 192, 192 = 0 mod 8.
// ---------------------------------------------------------------------------
__global__ __launch_bounds__(256) void gemm_qkv(
    const unsigned short* __restrict__ Xb,
    const unsigned short* __restrict__ Wq, const unsigned short* __restrict__ Wk,
    const unsigned short* __restrict__ Wv,
    const float* __restrict__ biasq, const float* __restrict__ biask,
    const float* __restrict__ biasv,
    const float2* __restrict__ rope,
    unsigned short* __restrict__ Qo, unsigned short* __restrict__ Ko,
    unsigned short* __restrict__ Vto) {
  const int bid = blockIdx.x;                 // 1536
  const int xg = bid / 192;                   // 0..7   n-block
  const int j  = bid % 192;                   // strip: j%8 = XCD for all xg
  const int yb = j % 64;                      // m-strip
  const int z  = j / 64;                      // 0..2
  __shared__ unsigned short As[128 * 64];
  __shared__ unsigned short Bs[128 * 64];
  const int t = threadIdx.x;
  const int lane = t & 63, w = t >> 6;
  const int wr = w >> 1, wc = w & 1;
  const int lc = lane & 15, lr = lane >> 4;

  int m0, n0;
  const unsigned short *Apt, *Bpt;
  if (z == 0)      { m0 = yb * 128; n0 = xg * 128; Apt = Xb; Bpt = Wq; }
  else if (z == 1) { m0 = yb * 128; n0 = xg * 128; Apt = Xb; Bpt = Wk; }
  else             { m0 = xg * 128; n0 = yb * 128; Apt = Wv; Bpt = Xb; }

  const int arow = t >> 3;
  const int acol = ((t & 7) << 3) ^ ((arow & 7) << 3);   // pre-swizzled source col
  const unsigned short* gA = Apt + (size_t)(m0 + arow) * 1024 + acol;
  const unsigned short* gB = Bpt + (size_t)(n0 + arow) * 1024 + acol;
  unsigned short* lA = As + t * 8;
  unsigned short* lB = Bs + t * 8;

  f32x4 acc[4][4];
#pragma unroll
  for (int m = 0; m < 4; ++m)
#pragma unroll
    for (int n = 0; n < 4; ++n) acc[m][n] = (f32x4){0.f, 0.f, 0.f, 0.f};

  const int rsw = (lc & 7) << 3;

#pragma unroll 1
  for (int kt = 0; kt < 16; ++kt) {
    __syncthreads();
#pragma unroll
    for (int c = 0; c < 4; ++c) {
      gload16(gA + (size_t)c * 32 * 1024, lA + c * 2048);
      gload16(gB + (size_t)c * 32 * 1024, lB + c * 2048);
    }
    gA += 64; gB += 64;
    __syncthreads();
#pragma unroll
    for (int ks = 0; ks < 2; ++ks) {
      bfrag af[4], bfr[4];
#pragma unroll
      for (int i = 0; i < 4; ++i)
        af[i] = *(const bfrag*)(As + (wr * 64 + i * 16 + lc) * 64 + ((ks * 32 + lr * 8) ^ rsw));
#pragma unroll
      for (int i = 0; i < 4; ++i)
        bfr[i] = *(const bfrag*)(Bs + (wc * 64 + i * 16 + lc) * 64 + ((ks * 32 + lr * 8) ^ rsw));
#pragma unroll
      for (int m = 0; m < 4; ++m)
#pragma unroll
        for (int n = 0; n < 4; ++n)
          acc[m][n] = MFMA16(af[m], bfr[n], acc[m][n]);
    }
  }

  if (z < 2) {
    // bias + RoPE + (Q only) 0.125*log2e scale; scatter to (B,H,S,D)
    const float* bias = (z == 0) ? biasq : biask;
    unsigned short* dst = (z == 0) ? Qo : Ko;
    const float qs = (z == 0) ? 0.125f * 1.44269504f : 1.0f;
    const int h = (n0 + wc * 64) >> 6;
#pragma unroll
    for (int m = 0; m < 4; ++m) {
#pragma unroll
      for (int r = 0; r < 4; ++r) {
        int row = m0 + wr * 64 + m * 16 + lr * 4 + r;   // token
        int b = row >> 11, s = row & 2047;
        const float2* trow = rope + (s << 5);
        size_t base = ((size_t)((b << 4) + h) * 2048 + s) * 64;
#pragma unroll
        for (int n = 0; n < 2; ++n) {
          int col1 = n0 + wc * 64 + n * 16 + lc;
          int d = n * 16 + lc;                           // < 32
          float a  = acc[m][n][r]     + bias[col1];
          float bb = acc[m][n + 2][r] + bias[col1 + 32];
          float2 t0 = trow[d >> 1];
          float2 t1 = trow[16 + (d >> 1)];
          dst[base + d]      = f2bf((a * t0.x - bb * t0.y) * qs);
          dst[base + d + 32] = f2bf((bb * t1.x + a * t1.y) * qs);
        }
      }
    }
  } else {
    // V: C[wcol][token] -> Vt (B,H,D,S)
#pragma unroll
    for (int m = 0; m < 4; ++m) {
#pragma unroll
      for (int r = 0; r < 4; ++r) {
        int wcol = m0 + wr * 64 + m * 16 + lr * 4 + r;
        float bv = biasv[wcol];
        int h = wcol >> 6, d = wcol & 63;
#pragma unroll
        for (int n = 0; n < 4; ++n) {
          int token = n0 + wc * 64 + n * 16 + lc;
          int b = token >> 11, s = token & 2047;
          Vto[((size_t)((b << 4) + h) * 64 + d) * 2048 + s] = f2bf(acc[m][n][r] + bv);
        }
      }
    }
  }
}

// ---------------------------------------------------------------------------
// K4: flash attention = ROUND-12 VERBATIM (best verified: 99.6 us).
// 32x32 MFMA, in-register P, 64 q-rows/wave, KVBLK=64, counted-vmcnt 2-deep
// prefetch, no-max softmax.  Post-r15 ledger: r10 (no staging), r13 (KVBLK=128),
// r14 (ILP reorder), r15 (split-K: VGPR spill -> 2.2 GB scratch traffic) all
// refuted — 2 waves/SIMD with ~124-VGPR state is this decomposition's
// structural operating point; do not touch without new counter evidence.
// ---------------------------------------------------------------------------
__global__ __launch_bounds__(256) void attn_kernel(
    const unsigned short* __restrict__ Q, const unsigned short* __restrict__ K,
    const unsigned short* __restrict__ Vt, unsigned short* __restrict__ O) {
  __shared__ unsigned short Ks[2][64 * 64];
  __shared__ unsigned short Vs[2][64 * 64];
  const int t = threadIdx.x;
  const int lane = t & 63, w = t >> 6;          // 4 waves
  const int l31 = lane & 31, th = lane >> 5;
  const int bid = blockIdx.x;                   // 512 = 8 xcd x 8 head x 8 qb
  const int xcd = bid & 7;
  const int jj = bid >> 3;                      // 0..63
  const int bh = xcd * 8 + (jj >> 3);           // 8 heads per XCD -> L2-resident
  const int qb = jj & 7;
  const int q0 = qb * 256 + w * 64;             // 64 q-rows per wave

  // Q B-fragments: bq{g}[kk] = Q[q=q0+g*32+l31][d = kk*16 + th*8 .. +7]
  const unsigned short* Qp = Q + ((size_t)bh * 2048 + q0 + l31) * 64 + th * 8;
  bfrag bq0[4], bq1[4];
#pragma unroll
  for (int kk = 0; kk < 4; ++kk) {
    bq0[kk] = *(const bfrag*)(Qp + kk * 16);
    bq1[kk] = *(const bfrag*)(Qp + 32 * 64 + kk * 16);
  }

  f32x16 acc00, acc01, acc10, acc11;   // acc{g}{db}: q-group g, d-block db
#pragma unroll
  for (int i = 0; i < 16; ++i) {
    acc00[i] = 0.f; acc01[i] = 0.f; acc10[i] = 0.f; acc11[i] = 0.f;
  }
  float lsum0 = 0.f, lsum1 = 0.f;

  const unsigned short* Kg = K + (size_t)bh * 2048 * 64;
  const unsigned short* Vg = Vt + (size_t)bh * 64 * 2048;

  const int rs = (l31 & 7) << 3;                 // frag-read swizzle

  const int srow = t >> 3;                       // 0..31
  const int scol = ((t & 7) ^ (srow & 7)) << 3;  // pre-swizzled source col

#define STAGE(bufi, kb_)                                                        \
  {                                                                             \
    gload16(Kg + (size_t)((kb_) + srow) * 64 + scol,        Ks[bufi] + t * 8);  \
    gload16(Kg + (size_t)((kb_) + 32 + srow) * 64 + scol,   Ks[bufi] + 2048 + t * 8); \
    gload16(Vg + (size_t)srow * 2048 + (kb_) + scol,        Vs[bufi] + t * 8);  \
    gload16(Vg + (size_t)(32 + srow) * 2048 + (kb_) + scol, Vs[bufi] + 2048 + t * 8); \
  }

  STAGE(0, 0);
  STAGE(1, 64);
  int cur = 0;

#pragma unroll 1
  for (int kt = 0; kt < 32; ++kt) {
    // wait for OWN tile's 4 loads (leave next tile's 4 in flight), then join
    if (kt < 30) { asm volatile("s_waitcnt vmcnt(4)" ::: "memory"); }
    else         { asm volatile("s_waitcnt vmcnt(0)" ::: "memory"); }
    __builtin_amdgcn_s_barrier();

    const unsigned short* KsC = Ks[cur];
    const unsigned short* VsC = Vs[cur];

    bfrag pa0[4], pa1[4];   // PV A-frags per q-group, one per 16-key slice

#pragma unroll
    for (int kb = 0; kb < 2; ++kb) {            // two 32-key blocks
      // K A-fragments loaded ONCE, reused by both q-groups
      const unsigned short* kp = KsC + (kb * 32 + l31) * 64;
      bfrag ka[4];
#pragma unroll
      for (int kk = 0; kk < 4; ++kk)
        ka[kk] = *(const bfrag*)(kp + ((kk * 16 + th * 8) ^ rs));

#pragma unroll
      for (int g = 0; g < 2; ++g) {
        // S^T block: rows=keys, cols=q (32 q of group g)
        f32x16 sc;
#pragma unroll
        for (int i = 0; i < 16; ++i) sc[i] = 0.f;
        __builtin_amdgcn_s_setprio(1);
#pragma unroll
        for (int kk = 0; kk < 4; ++kk)
          sc = MFMA32(ka[kk], g == 0 ? bq0[kk] : bq1[kk], sc);
        __builtin_amdgcn_s_setprio(0);

        // P = exp2(S) (no-max); accumulate this lane's q-row partial sum
#pragma unroll
        for (int i = 0; i < 16; ++i) sc[i] = __builtin_amdgcn_exp2f(sc[i]);
        {
          float s0 = (sc[0] + sc[1]) + (sc[2] + sc[3]);
          float s1 = (sc[4] + sc[5]) + (sc[6] + sc[7]);
          float s2 = (sc[8] + sc[9]) + (sc[10] + sc[11]);
          float s3 = (sc[12] + sc[13]) + (sc[14] + sc[15]);
          if (g == 0) lsum0 += (s0 + s1) + (s2 + s3);
          else        lsum1 += (s0 + s1) + (s2 + s3);
        }

        // pack pairs; one shfl_xor(32) per pair assembles the A-frags
        unsigned pk[4][2];
#pragma unroll
        for (int gg = 0; gg < 4; ++gg) {
          asm("v_cvt_pk_bf16_f32 %0, %1, %2"
              : "=v"(pk[gg][0]) : "v"(sc[4 * gg]), "v"(sc[4 * gg + 1]));
          asm("v_cvt_pk_bf16_f32 %0, %1, %2"
              : "=v"(pk[gg][1]) : "v"(sc[4 * gg + 2]), "v"(sc[4 * gg + 3]));
        }
#pragma unroll
        for (int ka2 = 0; ka2 < 2; ++ka2) {
          u32x4 pu;
#pragma unroll
          for (int j = 0; j < 2; ++j) {
            unsigned zlo = pk[2 * ka2][j];
            unsigned zhi = pk[2 * ka2 + 1][j];
            unsigned zsend = th ? zlo : zhi;
            unsigned wv = (unsigned)__shfl_xor((int)zsend, 32);
            pu[j]     = th ? wv : zlo;
            pu[2 + j] = th ? zhi : wv;
          }
          if (g == 0) pa0[kb * 2 + ka2] = __builtin_bit_cast(bfrag, pu);
          else        pa1[kb * 2 + ka2] = __builtin_bit_cast(bfrag, pu);
        }
      }
    }

    // O += P * V: V-frags loaded once per kg, reused by all 4 accumulators
    __builtin_amdgcn_s_setprio(1);
#pragma unroll
    for (int kg = 0; kg < 4; ++kg) {
      const unsigned short* vp0 = VsC + (size_t)l31 * 64;
      const unsigned short* vp1 = VsC + (size_t)(32 + l31) * 64;
      bfrag vb0 = *(const bfrag*)(vp0 + ((kg * 16 + th * 8) ^ rs));
      bfrag vb1 = *(const bfrag*)(vp1 + ((kg * 16 + th * 8) ^ rs));
      acc00 = MFMA32(pa0[kg], vb0, acc00);
      acc01 = MFMA32(pa0[kg], vb1, acc01);
      acc10 = MFMA32(pa1[kg], vb0, acc10);
      acc11 = MFMA32(pa1[kg], vb1, acc11);
    }
    __builtin_amdgcn_s_setprio(0);

    // all waves done reading buf[cur] -> safe to overwrite with tile kt+2
    __builtin_amdgcn_s_barrier();
    if (kt + 2 < 32) STAGE(cur, (kt + 2) * 64);
    cur ^= 1;
  }
#undef STAGE

  // row-sums: this lane covers one key-half of q = q0 + g*32 + l31
  float v0 = lsum0 + __shfl_xor(lsum0, 32);
  float v1 = lsum1 + __shfl_xor(lsum1, 32);
  float inv0 = 1.0f / v0;
  float inv1 = 1.0f / v1;

  // store O in (B,S,H,D) bf16; lane holds O[q=g*32+row(r)][d = 32*db + l31]
  const int b = bh >> 4, h = bh & 15;
#pragma unroll
  for (int r = 0; r < 16; ++r) {
    int qrow = (r & 3) + 8 * (r >> 2) + 4 * th;
    float invr0 = __shfl(inv0, qrow);            // lane qrow holds inv(q-group 0)
    float invr1 = __shfl(inv1, qrow);
    size_t base0 = (((size_t)b * 2048 + q0 + qrow) * 16 + h) * 64 + l31;
    size_t base1 = (((size_t)b * 2048 + q0 + 32 + qrow) * 16 + h) * 64 + l31;
    O[base0]      = f2bf(acc00[r] * invr0);
    O[base0 + 32] = f2bf(acc01[r] * invr0);
    O[base1]      = f2bf(acc10[r] * invr1);
    O[base1 + 32] = f2bf(acc11[r] * invr1);
  }
}

// ---------------------------------------------------------------------------
// K5: output projection, 1D grid XCD-GROUPED (T1) like gemm_qkv:
// bid = xg*64 + j, all 8 xg-blocks of m-strip j share bid = j (mod 8) -> same
// XCD -> shared O-strip L2-resident.  512 = 8 x 64, 64 = 0 mod 8.
// ---------------------------------------------------------------------------
__global__ __launch_bounds__(256) void gemm_out(
    const unsigned short* __restrict__ Ob, const unsigned short* __restrict__ Wo,
    const float* __restrict__ bias, float* __restrict__ out) {
  __shared__ unsigned short As[128 * 64];
  __shared__ unsigned short Bs[128 * 64];
  const int bid = blockIdx.x;                 // 512
  const int xg = bid / 64;                    // 0..7  n-block
  const int j  = bid % 64;                    // m-strip; j%8 = XCD
  const int t = threadIdx.x;
  const int lane = t & 63, w = t >> 6;
  const int wr = w >> 1, wc = w & 1;
  const int lc = lane & 15, lr = lane >> 4;
  const int m0 = j * 128, n0 = xg * 128;

  const int arow = t >> 3;
  const int acol = ((t & 7) << 3) ^ ((arow & 7) << 3);
  const unsigned short* gA = Ob + (size_t)(m0 + arow) * 1024 + acol;
  const unsigned short* gB = Wo + (size_t)(n0 + arow) * 1024 + acol;
  unsigned short* lA = As + t * 8;
  unsigned short* lB = Bs + t * 8;

  f32x4 acc[4][4];
#pragma unroll
  for (int m = 0; m < 4; ++m)
#pragma unroll
    for (int n = 0; n < 4; ++n) acc[m][n] = (f32x4){0.f, 0.f, 0.f, 0.f};

  const int rsw = (lc & 7) << 3;

#pragma unroll 1
  for (int kt = 0; kt < 16; ++kt) {
    __syncthreads();
#pragma unroll
    for (int c = 0; c < 4; ++c) {
      gload16(gA + (size_t)c * 32 * 1024, lA + c * 2048);
      gload16(gB + (size_t)c * 32 * 1024, lB + c * 2048);
    }
    gA += 64; gB += 64;
    __syncthreads();
#pragma unroll
    for (int ks = 0; ks < 2; ++ks) {
      bfrag af[4], bfr[4];
#pragma unroll
      for (int i = 0; i < 4; ++i)
        af[i] = *(const bfrag*)(As + (wr * 64 + i * 16 + lc) * 64 + ((ks * 32 + lr * 8) ^ rsw));
#pragma unroll
      for (int i = 0; i < 4; ++i)
        bfr[i] = *(const bfrag*)(Bs + (wc * 64 + i * 16 + lc) * 64 + ((ks * 32 + lr * 8) ^ rsw));
#pragma unroll
      for (int m = 0; m < 4; ++m)
#pragma unroll
        for (int n = 0; n < 4; ++n)
          acc[m][n] = MFMA16(af[m], bfr[n], acc[m][n]);
    }
  }
#pragma unroll
  for (int n = 0; n < 4; ++n) {
    int col = n0 + wc * 64 + n * 16 + lc;
    float bv = bias[col];
#pragma unroll
    for (int m = 0; m < 4; ++m) {
#pragma unroll
      for (int r = 0; r < 4; ++r) {
        int row = m0 + wr * 64 + m * 16 + lr * 4 + r;
        out[(size_t)row * 1024 + col] = acc[m][n][r] + bv;
      }
    }
  }
}

// ---------------------------------------------------------------------------
extern "C" void kernel_launch(void* const* d_in, const int* in_sizes, int n_in,
                              void* d_out, int out_size, void* d_ws, size_t ws_size,
                              hipStream_t stream) {
  (void)in_sizes; (void)n_in; (void)out_size; (void)ws_size;
  const float* x  = (const float*)d_in[0];
  const float* wq = (const float*)d_in[1];
  const float* bq = (const float*)d_in[2];
  const float* wk = (const float*)d_in[3];
  const float* bk = (const float*)d_in[4];
  const float* wv = (const float*)d_in[5];
  const float* bv = (const float*)d_in[6];
  const float* wo = (const float*)d_in[7];
  const float* bo = (const float*)d_in[8];
  float* out = (float*)d_out;

  char* ws = (char*)d_ws;
  unsigned short* Xb   = (unsigned short*)(ws);                       // 16 MB (reused as O)
  unsigned short* Wqb  = (unsigned short*)(ws + (16ull << 20));       // 2 MB
  unsigned short* Wkb  = (unsigned short*)(ws + (18ull << 20));
  unsigned short* Wvb  = (unsigned short*)(ws + (20ull << 20));
  unsigned short* Wob  = (unsigned short*)(ws + (22ull << 20));
  unsigned short* Qb   = (unsigned short*)(ws + (24ull << 20));       // 16 MB
  unsigned short* Kb   = (unsigned short*)(ws + (40ull << 20));       // 16 MB
  unsigned short* Vt   = (unsigned short*)(ws + (56ull << 20));       // 16 MB (B,H,D,S)
  float2* rope         = (float2*)(ws + (72ull << 20));               // 512 KB
  unsigned short* Ob   = Xb;   // Xb dead after QKV GEMM

  prep_kernel<<<dim3(1024, 6), 256, 0, stream>>>(x, wq, wk, wv, wo,
                                                 Xb, Wqb, Wkb, Wvb, Wob, rope);
  gemm_qkv<<<1536, 256, 0, stream>>>(Xb, Wqb, Wkb, Wvb,
                                     bq, bk, bv, rope, Qb, Kb, Vt);
  attn_kernel<<<512, 256, 0, stream>>>(Qb, Kb, Vt, Ob);
  gemm_out<<<512, 256, 0, stream>>>(Ob, Wob, bo, out);
}